// Round 17
// baseline (371.869 us; speedup 1.0000x reference)
//
#include <hip/hip_runtime.h>

// GraphSAGE 2-layer forward, MI355X. Round 16 (resubmit after broker timeout):
//  - gathers: 64-feat windows (full 128B-line node visits, half the L1
//    transactions of 32-feat) + NON-TEMPORAL stores for agg/out (write-set no
//    longer thrashes the L2 read window: R13's failure mode) + nt loads for
//    the streaming self addend. L2 set = 2.56MB window + 1.28MB csr < 4MiB.
//  - everything else unchanged from Round 15.
// A1b[20000][640] f16 = [x(300) | 0(20) | agg(300) | 0(20)]
// h1 = relu(A1b @ Wt1^T + b1) (f16)
// [t2 | self] = h1 @ [Wn2^T | Ws2^T]; out = mean_agg(t2) + self

typedef _Float16 f16;
typedef _Float16 f16x4 __attribute__((ext_vector_type(4)));
typedef _Float16 f16x8 __attribute__((ext_vector_type(8)));
typedef float f32x4 __attribute__((ext_vector_type(4)));
typedef unsigned short u16;

constexpr int NN = 20000;   // nodes
constexpr int NE = 640000;  // edges
constexpr int F0 = 300;     // in feats
constexpr int F1 = 512;     // hidden
constexpr int F2 = 256;     // classes
constexpr int KP1 = 640;    // padded concat-K for layer 1
constexpr int XOFF = 320;   // agg region start inside A1b row

// bijective XCD-contiguous swizzle (m204)
__device__ __forceinline__ int xcd_swz(int b, int nb) {
    int xcd = b & 7, loc = b >> 3;
    int q = nb >> 3, r = nb & 7;
    return (xcd < r ? xcd * (q + 1) : r * (q + 1) + (xcd - r) * q) + loc;
}

// ---------------- fused prep: conv_x | Wt1 | Wt2cat | degree count ----------------
// block ranges: [0,6250) conv_x, [6250,7530) w1, [7530,8554) w2cat, [8554,11054) count
__global__ __launch_bounds__(256) void prep_all_kernel(
    const float* __restrict__ x, const float* __restrict__ Ws1,
    const float* __restrict__ Wn1, const float* __restrict__ Ws2,
    const float* __restrict__ Wn2, const int* __restrict__ dst,
    f16* __restrict__ A1b, f16* __restrict__ Wt1, f16* __restrict__ Wt2cat,
    int* __restrict__ cnt)
{
    int b = blockIdx.x, t = threadIdx.x;
    if (b < 6250) {
        // conv_x: x f32 -> A1b cols 0..299 (f16); zero cols 300..319
        long idx = (long)b * 256 + t;  // m*80 + c
        int m = (int)(idx / 80), c = (int)(idx % 80);
        if (c < 75) {
            float4 v = *(const float4*)(x + (long)m * F0 + 4 * c);
            f16x4 h = {(f16)v.x, (f16)v.y, (f16)v.z, (f16)v.w};
            *(f16x4*)(A1b + (long)m * KP1 + 4 * c) = h;
        } else {
            f16x4 z = {};
            *(f16x4*)(A1b + (long)m * KP1 + 300 + (c - 75) * 4) = z;
        }
    } else if (b < 7530) {
        // Wt1[n][k]: k<300 -> Ws1[k][n]; 300..319 -> 0; 320..619 -> Wn1[k-320][n]; else 0
        int idx = (b - 6250) * 256 + t;
        int n = idx / KP1, k = idx % KP1;
        float v = 0.f;
        if (k < 300) v = Ws1[k * F1 + n];
        else if (k >= XOFF && k < XOFF + 300) v = Wn1[(k - XOFF) * F1 + n];
        Wt1[idx] = (f16)v;
    } else if (b < 8554) {
        // Wt2cat[n][k]: n<256 -> Wn2[k][n]; n>=256 -> Ws2[k][n-256]
        int idx = (b - 7530) * 256 + t;
        int n = idx / F1, k = idx % F1;
        float v = (n < F2) ? Wn2[k * F2 + n] : Ws2[k * F2 + (n - F2)];
        Wt2cat[idx] = (f16)v;
    } else {
        // degree count
        int e = (b - 8554) * 256 + t;
        if (e < NE) atomicAdd(&cnt[dst[e]], 1);
    }
}

// ---------------- CSR build ----------------
__global__ __launch_bounds__(1024) void scan_kernel(const int* __restrict__ cnt,
                                                    int* __restrict__ row_ptr,
                                                    int* __restrict__ cursor) {
    constexpr int CH = (NN + 1023) / 1024;  // 20
    __shared__ int part[1024];
    const int t = threadIdx.x;
    int base = t * CH;
    int s = 0;
    #pragma unroll
    for (int i = 0; i < CH; ++i) {
        int idx = base + i;
        if (idx < NN) s += cnt[idx];
    }
    part[t] = s;
    __syncthreads();
    #pragma unroll
    for (int off = 1; off < 1024; off <<= 1) {
        int v = (t >= off) ? part[t - off] : 0;
        __syncthreads();
        part[t] += v;
        __syncthreads();
    }
    int run = (t == 0) ? 0 : part[t - 1];
    #pragma unroll
    for (int i = 0; i < CH; ++i) {
        int idx = base + i;
        if (idx < NN) {
            row_ptr[idx] = run;
            cursor[idx] = run;
            run += cnt[idx];
        }
    }
    if (t == 1023) row_ptr[NN] = part[1023];
}

__global__ void fill_kernel(const int* __restrict__ src, const int* __restrict__ dst,
                            int* __restrict__ cursor, u16* __restrict__ csr16) {
    int e = blockIdx.x * 256 + threadIdx.x;
    if (e >= NE) return;
    int pos = atomicAdd(&cursor[dst[e]], 1);
    csr16[pos] = (u16)src[e];
}

// ---------------- merged chunk-major gathers (64-feat windows, nt stores) ----------------
// Work item g = (seg, node, lane8): seg-major; 8 lanes/node, f16x8 (16B) per lane
// -> one full 128B line per node visit. xcd_swz keeps each XCD on one window.
// nt stores keep the write stream from evicting the read window (R13 fix).

// gather1: reads A1b cols [seg*64, seg*64+64), writes mean to cols XOFF + same
__global__ __launch_bounds__(256) void gather1_kernel(const int* __restrict__ row_ptr,
                                                      const u16* __restrict__ csr,
                                                      f16* __restrict__ A1b) {
    int wid = xcd_swz(blockIdx.x, 5 * 625);
    int seg = wid / 625;
    int g = (wid % 625) * 256 + threadIdx.x;  // 0..159999
    int m = g >> 3;
    int off = seg * 64 + (g & 7) * 8;
    int beg = row_ptr[m], end = row_ptr[m + 1];
    f16x8 acc = {};
    int e = beg;
    for (; e + 8 <= end; e += 8) {
        int s0 = csr[e + 0], s1 = csr[e + 1], s2 = csr[e + 2], s3 = csr[e + 3];
        int s4 = csr[e + 4], s5 = csr[e + 5], s6 = csr[e + 6], s7 = csr[e + 7];
        f16x8 v0 = *(const f16x8*)(A1b + (long)s0 * KP1 + off);
        f16x8 v1 = *(const f16x8*)(A1b + (long)s1 * KP1 + off);
        f16x8 v2 = *(const f16x8*)(A1b + (long)s2 * KP1 + off);
        f16x8 v3 = *(const f16x8*)(A1b + (long)s3 * KP1 + off);
        f16x8 v4 = *(const f16x8*)(A1b + (long)s4 * KP1 + off);
        f16x8 v5 = *(const f16x8*)(A1b + (long)s5 * KP1 + off);
        f16x8 v6 = *(const f16x8*)(A1b + (long)s6 * KP1 + off);
        f16x8 v7 = *(const f16x8*)(A1b + (long)s7 * KP1 + off);
        acc += ((v0 + v1) + (v2 + v3)) + ((v4 + v5) + (v6 + v7));
    }
    for (; e < end; ++e) {
        int s = csr[e];
        acc += *(const f16x8*)(A1b + (long)s * KP1 + off);
    }
    float inv = 1.0f / fmaxf((float)(end - beg), 1.0f);
    f16x8 w;
    #pragma unroll
    for (int j = 0; j < 8; ++j) w[j] = (f16)((float)acc[j] * inv);
    __builtin_nontemporal_store(w, (f16x8*)(A1b + (long)m * KP1 + XOFF + off));
}

// gather2: out[m][c] = mean_e(t2[src][c]) + self[m][c]
__global__ __launch_bounds__(256) void gather2_kernel(const int* __restrict__ row_ptr,
                                                      const u16* __restrict__ csr,
                                                      const f16* __restrict__ t2,
                                                      const float* __restrict__ self,
                                                      float* __restrict__ out) {
    int wid = xcd_swz(blockIdx.x, 4 * 625);
    int seg = wid / 625;
    int g = (wid % 625) * 256 + threadIdx.x;
    int m = g >> 3;
    int off = seg * 64 + (g & 7) * 8;
    int beg = row_ptr[m], end = row_ptr[m + 1];
    f16x8 acc = {};
    int e = beg;
    for (; e + 8 <= end; e += 8) {
        int s0 = csr[e + 0], s1 = csr[e + 1], s2 = csr[e + 2], s3 = csr[e + 3];
        int s4 = csr[e + 4], s5 = csr[e + 5], s6 = csr[e + 6], s7 = csr[e + 7];
        f16x8 v0 = *(const f16x8*)(t2 + (long)s0 * F2 + off);
        f16x8 v1 = *(const f16x8*)(t2 + (long)s1 * F2 + off);
        f16x8 v2 = *(const f16x8*)(t2 + (long)s2 * F2 + off);
        f16x8 v3 = *(const f16x8*)(t2 + (long)s3 * F2 + off);
        f16x8 v4 = *(const f16x8*)(t2 + (long)s4 * F2 + off);
        f16x8 v5 = *(const f16x8*)(t2 + (long)s5 * F2 + off);
        f16x8 v6 = *(const f16x8*)(t2 + (long)s6 * F2 + off);
        f16x8 v7 = *(const f16x8*)(t2 + (long)s7 * F2 + off);
        acc += ((v0 + v1) + (v2 + v3)) + ((v4 + v5) + (v6 + v7));
    }
    for (; e < end; ++e) {
        int s = csr[e];
        acc += *(const f16x8*)(t2 + (long)s * F2 + off);
    }
    float inv = 1.0f / fmaxf((float)(end - beg), 1.0f);
    const float* sp = self + (long)m * F2 + off;
    f32x4 s0 = __builtin_nontemporal_load((const f32x4*)(sp));
    f32x4 s1 = __builtin_nontemporal_load((const f32x4*)(sp + 4));
    f32x4 w0 = {(float)acc[0]*inv + s0[0], (float)acc[1]*inv + s0[1],
                (float)acc[2]*inv + s0[2], (float)acc[3]*inv + s0[3]};
    f32x4 w1 = {(float)acc[4]*inv + s1[0], (float)acc[5]*inv + s1[1],
                (float)acc[6]*inv + s1[2], (float)acc[7]*inv + s1[3]};
    float* op = out + (long)m * F2 + off;
    __builtin_nontemporal_store(w0, (f32x4*)(op));
    __builtin_nontemporal_store(w1, (f32x4*)(op + 4));
}

// ---------------- f16 MFMA GEMM ----------------
// C = A[M][K] @ Bt[N][K]^T. BM=64, BN=128, BK=64; 4 waves (2x2), wave tile 32x64.
// MODE 1: h1 = relu(C + bias) (f16)
// MODE 2: n<F2 -> t2[m][n] = f16(C); n>=F2 -> self[m][n-F2] = C + bias[n-F2] (f32)
template<int MODE>
__global__ __launch_bounds__(256) void hgemm_kernel(
    const f16* __restrict__ A, const f16* __restrict__ Bt,
    const float* __restrict__ bias, float* __restrict__ out_f32,
    f16* __restrict__ out_f16, int M, int N, int K)
{
    __shared__ f16 As[64][72];
    __shared__ f16 Bs[128][72];

    const int t = threadIdx.x;
    const int lane = t & 63, wave = t >> 6;
    const int wr = wave >> 1, wc = wave & 1;
    const int m0 = blockIdx.x * 64, n0 = blockIdx.y * 128;
    const int ar = t >> 2, ac = (t & 3) * 16;
    const int br = t >> 1, bc = (t & 1) * 32;

    f32x4 acc[2][4] = {};

    for (int k0 = 0; k0 < K; k0 += 64) {
        {
            const f16* ga = A + (long)(m0 + ar) * K + k0 + ac;
            bool mok = (m0 + ar) < M;
            f16x8 v0 = mok ? *(const f16x8*)(ga + 0) : (f16x8){};
            f16x8 v1 = mok ? *(const f16x8*)(ga + 8) : (f16x8){};
            *(f16x8*)&As[ar][ac + 0] = v0;
            *(f16x8*)&As[ar][ac + 8] = v1;
        }
        {
            const f16* gb = Bt + (long)(n0 + br) * K + k0 + bc;
            f16x8 v0 = *(const f16x8*)(gb + 0);
            f16x8 v1 = *(const f16x8*)(gb + 8);
            f16x8 v2 = *(const f16x8*)(gb + 16);
            f16x8 v3 = *(const f16x8*)(gb + 24);
            *(f16x8*)&Bs[br][bc + 0]  = v0;
            *(f16x8*)&Bs[br][bc + 8]  = v1;
            *(f16x8*)&Bs[br][bc + 16] = v2;
            *(f16x8*)&Bs[br][bc + 24] = v3;
        }
        __syncthreads();
        #pragma unroll
        for (int kk = 0; kk < 2; ++kk) {
            f16x8 af[2], bf[4];
            #pragma unroll
            for (int i = 0; i < 2; ++i)
                af[i] = *(const f16x8*)&As[wr * 32 + i * 16 + (lane & 15)][kk * 32 + (lane >> 4) * 8];
            #pragma unroll
            for (int j = 0; j < 4; ++j)
                bf[j] = *(const f16x8*)&Bs[wc * 64 + j * 16 + (lane & 15)][kk * 32 + (lane >> 4) * 8];
            #pragma unroll
            for (int i = 0; i < 2; ++i)
                #pragma unroll
                for (int j = 0; j < 4; ++j)
                    acc[i][j] = __builtin_amdgcn_mfma_f32_16x16x32_f16(af[i], bf[j], acc[i][j], 0, 0, 0);
        }
        __syncthreads();
    }

    // C/D layout: col = lane&15, row = (lane>>4)*4 + q  [m89-verified]
    const int cr = (lane >> 4) * 4, cc = lane & 15;
    #pragma unroll
    for (int i = 0; i < 2; ++i) {
        #pragma unroll
        for (int j = 0; j < 4; ++j) {
            int n = n0 + wc * 64 + j * 16 + cc;
            float b;
            if (MODE == 1) b = bias[n];
            else           b = (n >= F2) ? bias[n - F2] : 0.f;
            #pragma unroll
            for (int q = 0; q < 4; ++q) {
                int m = m0 + wr * 32 + i * 16 + cr + q;
                if (m >= M) continue;
                float v = acc[i][j][q];
                if (MODE == 1) {
                    out_f16[(long)m * N + n] = (f16)fmaxf(v + b, 0.f);
                } else {
                    if (n < F2) out_f16[(long)m * F2 + n] = (f16)v;
                    else        out_f32[(long)m * F2 + (n - F2)] = v + b;
                }
            }
        }
    }
}

extern "C" void kernel_launch(void* const* d_in, const int* in_sizes, int n_in,
                              void* d_out, int out_size, void* d_ws, size_t ws_size,
                              hipStream_t stream) {
    const float* x   = (const float*)d_in[0];
    const float* Ws1 = (const float*)d_in[1];
    const float* Wn1 = (const float*)d_in[2];
    const float* b1  = (const float*)d_in[3];
    const float* Ws2 = (const float*)d_in[4];
    const float* Wn2 = (const float*)d_in[5];
    const float* b2  = (const float*)d_in[6];
    const int* src   = (const int*)d_in[7];
    const int* dst   = (const int*)d_in[8];
    float* out = (float*)d_out;

    // workspace layout (bytes, 16B aligned):
    char* ws = (char*)d_ws;
    int* row_ptr = (int*)(ws);                      // 20001 i32   [0 .. 80,064)
    u16* csr16   = (u16*)(ws + 80064);              // 640000 u16  [.. 1,360,064)
    int* cursor  = (int*)(ws + 1360064);            // 20000 i32   [.. 1,440,064)
    f16* A1b     = (f16*)(ws + 1440064);            // 20000x640   [.. 27,040,064)
    f16* h1      = (f16*)(ws + 27040064);           // 20000x512   [.. 47,520,064)
    f16* t2      = (f16*)(ws + 47520064);           // 20000x256   [.. 57,760,064)
    float* selfp = (float*)(ws + 57760064);         // 20000x256 f32 [.. 78,240,064)
    f16* Wt1     = (f16*)(ws + 78240064);           // 512x640     [.. 78,895,424)
    f16* Wt2cat  = (f16*)(ws + 78895424);           // 512x512     [.. 79,419,712)

    // ---- fused prep (conv_x | Wt1 | Wt2cat | count) + CSR build ----
    hipMemsetAsync(cursor, 0, NN * sizeof(int), stream);
    prep_all_kernel<<<11054, 256, 0, stream>>>(x, Ws1, Wn1, Ws2, Wn2, dst,
                                               A1b, Wt1, Wt2cat, cursor);
    scan_kernel<<<1, 1024, 0, stream>>>(cursor, row_ptr, cursor);
    fill_kernel<<<(NE + 255) / 256, 256, 0, stream>>>(src, dst, cursor, csr16);

    // ---- layer 1: merged gather (64-feat windows, nt stores), concat-GEMM + relu ----
    gather1_kernel<<<5 * 625, 256, 0, stream>>>(row_ptr, csr16, A1b);
    dim3 g1((NN + 63) / 64, F1 / 128);
    hgemm_kernel<1><<<g1, 256, 0, stream>>>(A1b, Wt1, b1, nullptr, h1, NN, F1, KP1);

    // ---- layer 2: fused [t2 | self] GEMM, then merged gather+add ----
    dim3 g2((NN + 63) / 64, (2 * F2) / 128);
    hgemm_kernel<2><<<g2, 256, 0, stream>>>(h1, Wt2cat, b2, selfp, t2, NN, 2 * F2, F1);
    gather2_kernel<<<4 * 625, 256, 0, stream>>>(row_ptr, csr16, t2, selfp, out);
}